// Round 1
// baseline (279.142 us; speedup 1.0000x reference)
//
#include <hip/hip_runtime.h>
#include <math.h>

#define NN 100000
#define NE 3200000
#define NR 90
#define NB 782          // buckets of 128 nodes (dst>>7)
#define CH 4096         // edges per block in pass1
#define NCHUNK 782      // ceil(NE/CH)
#define CAP 6144        // padded per-bucket capacity (mean 4096, +32 sigma)

typedef unsigned int u32;
typedef unsigned short u16;

__device__ inline u32 pack2(float a, float b) {       // bf16(a) lo16, bf16(b) hi16 (RNE)
    u32 ua = __float_as_uint(a); ua += 0x7FFFu + ((ua >> 16) & 1u);
    u32 ub = __float_as_uint(b); ub += 0x7FFFu + ((ub >> 16) & 1u);
    return (ua >> 16) | (ub & 0xFFFF0000u);
}
__device__ inline float unlo(u32 w) { return __uint_as_float(w << 16); }
__device__ inline float unhi(u32 w) { return __uint_as_float(w & 0xFFFF0000u); }

// ---------------- pass 1: direct padded-bucket partition (no pre-count) ----------------
// tmp entry: (dst&127)<<25 | src<<7 | et ; bucket b's window is tmp[b*CAP ..]
__global__ __launch_bounds__(512) void pass1_kernel(const int* __restrict__ src,
                                                    const int* __restrict__ dst,
                                                    const int* __restrict__ et,
                                                    u32* __restrict__ ccursor,
                                                    u32* __restrict__ tmp) {
    __shared__ u32 cntA[NB];
    __shared__ u32 lcur[NB];
    __shared__ u32 delta[NB];
    __shared__ u32 scanS[512];
    __shared__ u32 lrecs[CH];
    __shared__ u16 lbid[CH];
    int tid = threadIdx.x;
    int c0 = blockIdx.x * CH;
    int c1 = c0 + CH; if (c1 > NE) c1 = NE;
    int nloc = c1 - c0;

    for (int i = tid; i < NB; i += 512) cntA[i] = 0;
    __syncthreads();

    // batch dst loads into registers (reused in scatter phase)
    u32 dcache[8];
#pragma unroll
    for (int i = 0; i < 8; i++) {
        int e = c0 + tid + i * 512;
        dcache[i] = (e < c1) ? (u32)dst[e] : 0xFFFFFFFFu;
    }
#pragma unroll
    for (int i = 0; i < 8; i++)
        if (dcache[i] != 0xFFFFFFFFu) atomicAdd(&cntA[dcache[i] >> 7], 1u);
    __syncthreads();

    // pairwise inclusive scan over NB=782 buckets with 512 threads
    int i0 = 2 * tid, i1 = 2 * tid + 1;
    u32 ca = (i0 < NB) ? cntA[i0] : 0u;
    u32 cb = (i1 < NB) ? cntA[i1] : 0u;
    scanS[tid] = ca + cb;
    __syncthreads();
#pragma unroll
    for (int ofs = 1; ofs < 512; ofs <<= 1) {
        u32 v = (tid >= ofs) ? scanS[tid - ofs] : 0u;
        __syncthreads();
        scanS[tid] += v;
        __syncthreads();
    }
    u32 exc = (tid == 0) ? 0u : scanS[tid - 1];
    if (i0 < NB) {
        lcur[i0] = exc;
        delta[i0] = ca ? ((u32)i0 * CAP + atomicAdd(&ccursor[i0], ca) - exc) : 0u;
    }
    if (i1 < NB) {
        u32 e1 = exc + ca;
        lcur[i1] = e1;
        delta[i1] = cb ? ((u32)i1 * CAP + atomicAdd(&ccursor[i1], cb) - e1) : 0u;
    }
    __syncthreads();

#pragma unroll
    for (int i = 0; i < 8; i++) {
        int e = c0 + tid + i * 512;
        if (e < c1) {
            u32 d = dcache[i];
            u32 bb = d >> 7;
            u32 pos = atomicAdd(&lcur[bb], 1u);
            lrecs[pos] = ((d & 127u) << 25) | ((u32)src[e] << 7) | (u32)et[e];
            lbid[pos] = (u16)bb;
        }
    }
    __syncthreads();

    for (int k = tid; k < nloc; k += 512)
        tmp[delta[lbid[k]] + k] = lrecs[k];
}

// ---------------- pass 2 + layer 1 fused (512 threads, 128-node bucket) ----------------
// A': batched tmp loads (MLP) then per-(node,rel) LDS atomics; B: degree scan;
// C: scatter final recs (count embedded) to global AND LDS; E: layer1 from LDS recs.
#define CNTW (128 * 23)
__global__ __launch_bounds__(512) void pass2_kernel(const u32* __restrict__ tmp,
                                                    const u32* __restrict__ ccursor,
                                                    u32* __restrict__ off2,
                                                    u32* __restrict__ recs,
                                                    const float* __restrict__ x,
                                                    const float* __restrict__ w1,
                                                    const float* __restrict__ root1,
                                                    const float* __restrict__ b1,
                                                    uint4* __restrict__ h1b) {
    __shared__ u32 lc2[128];         // per-node cursor (relative)
    __shared__ u32 cnt32[CNTW];      // per-(node,rel) u8 counts packed 4/word
    __shared__ u32 sh[128];          // inclusive degree scan (survives all phases)
    __shared__ u32 lrec[CAP];        // sorted recs mirror for phase E
    int tid = threadIdx.x;
    int b = blockIdx.x;
    u32 r0 = (u32)b * CAP;
    u32 r1 = r0 + ccursor[b];        // cursor's final value == bucket edge count

    for (int i = tid; i < CNTW; i += 512) cnt32[i] = 0;
    __syncthreads();

    // A': issue ALL loads first (12 in flight), then consume with atomics
    u32 cached[12];                  // CAP/512 = 12 max entries per thread
#pragma unroll
    for (int i = 0; i < 12; i++) {
        u32 k = r0 + (u32)tid + (u32)i * 512u;
        cached[i] = (k < r1) ? tmp[k] : 0xFFFFFFFFu;
    }
#pragma unroll
    for (int i = 0; i < 12; i++) {
        u32 v = cached[i];
        if (v != 0xFFFFFFFFu) {
            u32 ln = v >> 25, rel = v & 127u;
            atomicAdd(&cnt32[ln * 23 + (rel >> 2)], 1u << ((rel & 3u) * 8u));
        }
    }
    __syncthreads();

    // A2: per-node degree = bytewise sum of own 23-word slice (no atomics)
    if (tid < 128) {
        u32 s = 0;
#pragma unroll
        for (int i = 0; i < 23; i++) {
            u32 w = cnt32[tid * 23 + i];
            s += (w & 255u) + ((w >> 8) & 255u) + ((w >> 16) & 255u) + (w >> 24);
        }
        sh[tid] = s;
    }
    __syncthreads();

    // B: inclusive scan of degrees (128 entries)
#pragma unroll
    for (int ofs = 1; ofs < 128; ofs <<= 1) {
        u32 v = (tid >= ofs && tid < 128) ? sh[tid - ofs] : 0u;
        __syncthreads();
        if (tid < 128) sh[tid] += v;
        __syncthreads();
    }
    int n = b * 128 + tid;
    if (tid < 128) {
        u32 excl = (tid == 0) ? 0u : sh[tid - 1];
        u32 deg = sh[tid] - excl;
        if (n < NN) off2[n] = (deg << 23) | (r0 + excl);   // start < 2^23, deg < 2^9
        lc2[tid] = excl;
    }
    __syncthreads();

    // C: scatter final recs — cnt32 complete, embed count byte; mirror into LDS
#pragma unroll
    for (int i = 0; i < 12; i++) {
        u32 v = cached[i];
        if (v != 0xFFFFFFFFu) {
            u32 ln = v >> 25, rel = v & 127u;
            u32 c = (cnt32[ln * 23 + (rel >> 2)] >> ((rel & 3u) * 8u)) & 255u;
            u32 pos = atomicAdd(&lc2[ln], 1u);
            u32 rr = (c << 24) | (v & 0xFFFFFFu);
            recs[r0 + pos] = rr;
            lrec[pos] = rr;
        }
    }
    __syncthreads();

    // E: layer 1 for this bucket's 128 nodes — 8 lanes/node, recs from LDS
#pragma unroll
    for (int g = 0; g < 2; g++) {
        int ln = g * 64 + (tid >> 3);          // 0..127
        int r = tid & 7;
        int nn = b * 128 + ln;
        float acc[8];
#pragma unroll
        for (int j = 0; j < 8; j++) acc[j] = 0.0f;
        if (nn < NN) {
            u32 k0l = (ln == 0) ? 0u : sh[ln - 1];
            u32 k1l = sh[ln];
            for (u32 k = k0l + r; k < k1l; k += 8) {
                u32 rec = lrec[k];
                u32 t = rec & 127u, s = (rec >> 7) & 0x1FFFFu;
                float norm = 1.0f / (float)(rec >> 24);
                float4 xv = *(const float4*)(x + (size_t)s * 4);
                float x0 = xv.x * norm, x1 = xv.y * norm;
                float x2 = xv.z * norm, x3 = xv.w * norm;
                const float4* wp = (const float4*)(w1 + (size_t)t * 16);  // [2][2][4]
                float4 wA = wp[0], wB = wp[1], wC = wp[2], wD = wp[3];
                acc[0] += x0 * wA.x + x1 * wB.x;
                acc[1] += x0 * wA.y + x1 * wB.y;
                acc[2] += x0 * wA.z + x1 * wB.z;
                acc[3] += x0 * wA.w + x1 * wB.w;
                acc[4] += x2 * wC.x + x3 * wD.x;
                acc[5] += x2 * wC.y + x3 * wD.y;
                acc[6] += x2 * wC.z + x3 * wD.z;
                acc[7] += x2 * wC.w + x3 * wD.w;
            }
        }
#pragma unroll
        for (int j = 0; j < 8; j++) {
            acc[j] += __shfl_xor(acc[j], 1);
            acc[j] += __shfl_xor(acc[j], 2);
            acc[j] += __shfl_xor(acc[j], 4);
        }
        if (r == 0 && nn < NN) {
            float4 xn = *(const float4*)(x + (size_t)nn * 4);
            float h[8];
#pragma unroll
            for (int j = 0; j < 8; j++) {
                float v = acc[j] + b1[j] + xn.x * root1[j] + xn.y * root1[8 + j]
                        + xn.z * root1[16 + j] + xn.w * root1[24 + j];
                h[j] = fmaxf(v, 0.0f);
            }
            h1b[nn] = make_uint4(pack2(h[0], h[1]), pack2(h[2], h[3]),
                                 pack2(h[4], h[5]), pack2(h[6], h[7]));
        }
    }
}

// ======== layers 2/3: 32 lanes/node (shallow gather chain), bf16 tables ========

// ---------------- layer 2: add-aggr + root + bias + relu ----------------
__global__ __launch_bounds__(256) void layer2_kernel(
        const u32* __restrict__ off2, const u32* __restrict__ recs,
        const uint4* __restrict__ h1b,
        const float* __restrict__ w2, const float* __restrict__ root2,
        const float* __restrict__ b2, u32* __restrict__ h2b) {
    int gid = blockIdx.x * 256 + threadIdx.x;
    int n = gid >> 5, r = gid & 31;
    if (n >= NN) return;
    float acc[12];
#pragma unroll
    for (int j = 0; j < 12; j++) acc[j] = 0.0f;

    u32 ov = off2[n];
    u32 k0 = ov & 0x7FFFFFu;
    u32 k1 = k0 + (ov >> 23);
    for (u32 k = k0 + r; k < k1; k += 32) {
        u32 rec = recs[k];
        u32 t = rec & 127u, s = (rec >> 7) & 0x1FFFFu;
        uint4 hw = h1b[s];
        float a0 = unlo(hw.x), a1 = unhi(hw.x), a2 = unlo(hw.y), a3 = unhi(hw.y);
        float a4 = unlo(hw.z), a5 = unhi(hw.z), a6 = unlo(hw.w), a7 = unhi(hw.w);
        const float4* wp = (const float4*)(w2 + (size_t)t * 24);   // [4][2][3]
        float4 w0 = wp[0], w1v = wp[1], w2v = wp[2], w3v = wp[3], w4v = wp[4], w5v = wp[5];
        acc[0]  += a0 * w0.x  + a1 * w0.w;
        acc[1]  += a0 * w0.y  + a1 * w1v.x;
        acc[2]  += a0 * w0.z  + a1 * w1v.y;
        acc[3]  += a2 * w1v.z + a3 * w2v.y;
        acc[4]  += a2 * w1v.w + a3 * w2v.z;
        acc[5]  += a2 * w2v.x + a3 * w2v.w;
        acc[6]  += a4 * w3v.x + a5 * w3v.w;
        acc[7]  += a4 * w3v.y + a5 * w4v.x;
        acc[8]  += a4 * w3v.z + a5 * w4v.y;
        acc[9]  += a6 * w4v.z + a7 * w5v.y;
        acc[10] += a6 * w4v.w + a7 * w5v.z;
        acc[11] += a6 * w5v.x + a7 * w5v.w;
    }
#pragma unroll
    for (int j = 0; j < 12; j++) {
        acc[j] += __shfl_xor(acc[j], 1);
        acc[j] += __shfl_xor(acc[j], 2);
        acc[j] += __shfl_xor(acc[j], 4);
        acc[j] += __shfl_xor(acc[j], 8);
        acc[j] += __shfl_xor(acc[j], 16);
    }
    if (r != 0) return;
    uint4 hn = h1b[n];
    float hv[8] = { unlo(hn.x), unhi(hn.x), unlo(hn.y), unhi(hn.y),
                    unlo(hn.z), unhi(hn.z), unlo(hn.w), unhi(hn.w) };
    float h[12];
#pragma unroll
    for (int j = 0; j < 12; j++) {
        float v = acc[j] + b2[j];
#pragma unroll
        for (int i = 0; i < 8; i++) v += hv[i] * root2[i * 12 + j];
        h[j] = fmaxf(v, 0.0f);
    }
    u32* hb = h2b + (size_t)n * 8;             // 32B stride, 24B used
    *(uint4*)hb = make_uint4(pack2(h[0], h[1]), pack2(h[2], h[3]),
                             pack2(h[4], h[5]), pack2(h[6], h[7]));
    *(uint2*)(hb + 4) = make_uint2(pack2(h[8], h[9]), pack2(h[10], h[11]));
}

// ---------------- layer 3: mean-aggr + root + bias + log_softmax ----------------
__global__ __launch_bounds__(256) void layer3_kernel(
        const u32* __restrict__ off2, const u32* __restrict__ recs,
        const u32* __restrict__ h2b,
        const float* __restrict__ w3, const float* __restrict__ root3,
        const float* __restrict__ b3, float* __restrict__ out) {
    int gid = blockIdx.x * 256 + threadIdx.x;
    int n = gid >> 5, r = gid & 31;
    if (n >= NN) return;
    float acc[4] = {0.0f, 0.0f, 0.0f, 0.0f};
    u32 ov = off2[n];
    u32 k0 = ov & 0x7FFFFFu;
    u32 k1 = k0 + (ov >> 23);
    for (u32 k = k0 + r; k < k1; k += 32) {
        u32 rec = recs[k];
        u32 t = rec & 127u, s = (rec >> 7) & 0x1FFFFu;
        float norm = 1.0f / (float)(rec >> 24);
        const u32* hb = h2b + (size_t)s * 8;
        uint4 q = *(const uint4*)hb;
        uint2 p = *(const uint2*)(hb + 4);
        float hsv[12] = { unlo(q.x), unhi(q.x), unlo(q.y), unhi(q.y),
                          unlo(q.z), unhi(q.z), unlo(q.w), unhi(q.w),
                          unlo(p.x), unhi(p.x), unlo(p.y), unhi(p.y) };
        float wv[24];
        const float4* wp = (const float4*)(w3 + (size_t)t * 24);   // [2][6][2]
#pragma unroll
        for (int q4 = 0; q4 < 6; q4++) *(float4*)(wv + q4 * 4) = wp[q4];
        float m0 = 0.0f, m1 = 0.0f, m2 = 0.0f, m3 = 0.0f;
#pragma unroll
        for (int i = 0; i < 6; i++) {
            m0 += hsv[i] * wv[i * 2];          m1 += hsv[i] * wv[i * 2 + 1];
            m2 += hsv[6 + i] * wv[12 + i * 2]; m3 += hsv[6 + i] * wv[12 + i * 2 + 1];
        }
        acc[0] += m0 * norm; acc[1] += m1 * norm;
        acc[2] += m2 * norm; acc[3] += m3 * norm;
    }
#pragma unroll
    for (int j = 0; j < 4; j++) {
        acc[j] += __shfl_xor(acc[j], 1);
        acc[j] += __shfl_xor(acc[j], 2);
        acc[j] += __shfl_xor(acc[j], 4);
        acc[j] += __shfl_xor(acc[j], 8);
        acc[j] += __shfl_xor(acc[j], 16);
    }
    if (r != 0) return;
    const u32* hbn = h2b + (size_t)n * 8;
    uint4 qn = *(const uint4*)hbn; uint2 pn = *(const uint2*)(hbn + 4);
    float hv[12] = { unlo(qn.x), unhi(qn.x), unlo(qn.y), unhi(qn.y),
                     unlo(qn.z), unhi(qn.z), unlo(qn.w), unhi(qn.w),
                     unlo(pn.x), unhi(pn.x), unlo(pn.y), unhi(pn.y) };
    float t4[4];
#pragma unroll
    for (int j = 0; j < 4; j++) {
        float v = acc[j] + b3[j];
#pragma unroll
        for (int i = 0; i < 12; i++) v += hv[i] * root3[i * 4 + j];
        t4[j] = v;
    }
    float m = fmaxf(fmaxf(t4[0], t4[1]), fmaxf(t4[2], t4[3]));
    float s = 0.0f;
#pragma unroll
    for (int j = 0; j < 4; j++) s += __expf(t4[j] - m);
    float lse = m + __logf(s);
    *(float4*)(out + (size_t)n * 4) =
        make_float4(t4[0] - lse, t4[1] - lse, t4[2] - lse, t4[3] - lse);
}

extern "C" void kernel_launch(void* const* d_in, const int* in_sizes, int n_in,
                              void* d_out, int out_size, void* d_ws, size_t ws_size,
                              hipStream_t stream) {
    const float* x     = (const float*)d_in[0];
    const int*   ei    = (const int*)d_in[1];   // [2, E]
    const int*   etype = (const int*)d_in[2];
    const float* w1    = (const float*)d_in[3];
    const float* root1 = (const float*)d_in[4];
    const float* b1    = (const float*)d_in[5];
    const float* w2    = (const float*)d_in[6];
    const float* root2 = (const float*)d_in[7];
    const float* b2    = (const float*)d_in[8];
    const float* w3    = (const float*)d_in[9];
    const float* root3 = (const float*)d_in[10];
    const float* b3    = (const float*)d_in[11];
    float* out = (float*)d_out;

    const int* src = ei;
    const int* dst = ei + NE;

    // workspace layout (bytes):
    //   ccursor : [NB]      u32   @ 0           (3,128 -> pad 3,200)
    //   off2    : [NN]      u32   @ 3,200       (400,000 -> ends 403,200)
    //   tmp     : [NB*CAP]  u32   @ 403,200     (19,218,432 -> ends 19,621,632)
    //   recs    : [NB*CAP]  u32   @ 19,621,632  (19,218,432 -> ends 38,840,064)
    //   h1b     : [NN]      16B   @ 38,840,064  ( 1,600,000 -> ends 40,440,064)
    //   h2b     : [NN]      32B   @ 40,440,064  ( 3,200,000 -> total 43,640,064)
    char* ws = (char*)d_ws;
    u32*   ccursor = (u32*)ws;
    u32*   off2    = (u32*)(ws + 3200);
    u32*   tmp     = (u32*)(ws + 403200);
    u32*   recs    = (u32*)(ws + 19621632);
    uint4* h1b     = (uint4*)(ws + 38840064);
    u32*   h2b     = (u32*)(ws + 40440064);

    hipMemsetAsync(ccursor, 0, NB * sizeof(u32), stream);

    dim3 pgrid(NCHUNK);                      // 782
    dim3 ngrid(NB);                          // 782
    dim3 lgrid((NN * 32 + 255) / 256);       // 12500 (32 lanes/node)

    pass1_kernel<<<pgrid, 512, 0, stream>>>(src, dst, etype, ccursor, tmp);
    pass2_kernel<<<ngrid, 512, 0, stream>>>(tmp, ccursor, off2, recs, x, w1, root1, b1, h1b);
    layer2_kernel<<<lgrid, 256, 0, stream>>>(off2, recs, h1b, w2, root2, b2, h2b);
    layer3_kernel<<<lgrid, 256, 0, stream>>>(off2, recs, h2b, w3, root3, b3, out);
}

// Round 2
// 257.653 us; speedup vs baseline: 1.0834x; 1.0834x over previous
//
#include <hip/hip_runtime.h>
#include <math.h>

#define NN 100000
#define NE 3200000
#define NR 90
#define NB 782          // buckets of 128 nodes (dst>>7)
#define CH 4096         // edges per chunk
#define NCHUNK 782      // ceil(NE/CH)
#define CAP 6144        // padded per-bucket capacity (mean 4096, +32 sigma)

typedef unsigned int u32;
typedef unsigned short u16;

__device__ inline u32 pack2(float a, float b) {       // bf16(a) lo16, bf16(b) hi16 (RNE)
    u32 ua = __float_as_uint(a); ua += 0x7FFFu + ((ua >> 16) & 1u);
    u32 ub = __float_as_uint(b); ub += 0x7FFFu + ((ub >> 16) & 1u);
    return (ua >> 16) | (ub & 0xFFFF0000u);
}
__device__ inline float unlo(u32 w) { return __uint_as_float(w << 16); }
__device__ inline float unhi(u32 w) { return __uint_as_float(w & 0xFFFF0000u); }

// ============ pass 1 (deterministic, ZERO global atomics) ============
// P1a: per-chunk histogram -> cntmat[chunk][NB]
__global__ __launch_bounds__(512) void count_kernel(const int* __restrict__ dst,
                                                    u32* __restrict__ cntmat) {
    __shared__ u32 cntA[NB];
    int tid = threadIdx.x;
    int c0 = blockIdx.x * CH;
    int c1 = c0 + CH; if (c1 > NE) c1 = NE;
    for (int i = tid; i < NB; i += 512) cntA[i] = 0;
    __syncthreads();
    for (int e = c0 + tid; e < c1; e += 512)
        atomicAdd(&cntA[(u32)dst[e] >> 7], 1u);
    __syncthreads();
    for (int i = tid; i < NB; i += 512)
        cntmat[(size_t)blockIdx.x * NB + i] = cntA[i];
}

// P1b: per-bucket exclusive scan over chunks -> offT[bucket][NCHUNK]; totals -> bucketcnt
__global__ __launch_bounds__(512) void scan_kernel(const u32* __restrict__ cntmat,
                                                   u32* __restrict__ offT,
                                                   u32* __restrict__ bucketcnt) {
    __shared__ u32 scanS[512];
    int tid = threadIdx.x, b = blockIdx.x;
    int c0 = 2 * tid, c1 = 2 * tid + 1;
    u32 a  = (c0 < NCHUNK) ? cntmat[(size_t)c0 * NB + b] : 0u;
    u32 bb = (c1 < NCHUNK) ? cntmat[(size_t)c1 * NB + b] : 0u;
    scanS[tid] = a + bb;
    __syncthreads();
#pragma unroll
    for (int ofs = 1; ofs < 512; ofs <<= 1) {
        u32 v = (tid >= ofs) ? scanS[tid - ofs] : 0u;
        __syncthreads();
        scanS[tid] += v;
        __syncthreads();
    }
    u32 excl = (tid == 0) ? 0u : scanS[tid - 1];
    if (c0 < NCHUNK) offT[(size_t)b * NCHUNK + c0] = excl;
    if (c1 < NCHUNK) offT[(size_t)b * NCHUNK + c1] = excl + a;
    if (tid == (NCHUNK - 1) / 2) bucketcnt[b] = scanS[(NCHUNK - 1) / 2];
}

// P1c: scatter with precomputed bases; LDS-staged coalesced global write
// tmp entry: (dst&127)<<25 | src<<7 | et ; bucket b's window is tmp[b*CAP ..]
__global__ __launch_bounds__(512) void scatter_kernel(const int* __restrict__ src,
                                                      const int* __restrict__ dst,
                                                      const int* __restrict__ et,
                                                      const u32* __restrict__ cntmat,
                                                      const u32* __restrict__ offT,
                                                      u32* __restrict__ tmp) {
    __shared__ u32 lcur[NB];
    __shared__ u32 delta[NB];
    __shared__ u32 scanS[512];
    __shared__ u32 lrecs[CH];
    __shared__ u16 lbid[CH];
    int tid = threadIdx.x, ck = blockIdx.x;
    int c0 = ck * CH;
    int c1 = c0 + CH; if (c1 > NE) c1 = NE;
    int nloc = c1 - c0;

    // local scan of this chunk's bucket counts (read from cntmat, no recount)
    int i0 = 2 * tid, i1 = 2 * tid + 1;
    u32 ca = (i0 < NB) ? cntmat[(size_t)ck * NB + i0] : 0u;
    u32 cb = (i1 < NB) ? cntmat[(size_t)ck * NB + i1] : 0u;
    scanS[tid] = ca + cb;
    __syncthreads();
#pragma unroll
    for (int ofs = 1; ofs < 512; ofs <<= 1) {
        u32 v = (tid >= ofs) ? scanS[tid - ofs] : 0u;
        __syncthreads();
        scanS[tid] += v;
        __syncthreads();
    }
    u32 exc = (tid == 0) ? 0u : scanS[tid - 1];
    if (i0 < NB) {
        lcur[i0] = exc;
        delta[i0] = (u32)i0 * CAP + offT[(size_t)i0 * NCHUNK + ck] - exc;
    }
    if (i1 < NB) {
        u32 e1 = exc + ca;
        lcur[i1] = e1;
        delta[i1] = (u32)i1 * CAP + offT[(size_t)i1 * NCHUNK + ck] - e1;
    }
    __syncthreads();

    for (int e = c0 + tid; e < c1; e += 512) {
        u32 d = (u32)dst[e];
        u32 b = d >> 7;
        u32 pos = atomicAdd(&lcur[b], 1u);
        lrecs[pos] = ((d & 127u) << 25) | ((u32)src[e] << 7) | (u32)et[e];
        lbid[pos] = (u16)b;
    }
    __syncthreads();

    for (int k = tid; k < nloc; k += 512)
        tmp[delta[lbid[k]] + k] = lrecs[k];
}

// ---------------- pass 2 + layer 1 fused (512 threads, 128-node bucket) ----------------
#define CNTW (128 * 23)
__global__ __launch_bounds__(512) void pass2_kernel(const u32* __restrict__ tmp,
                                                    const u32* __restrict__ ccursor,
                                                    u32* __restrict__ off2,
                                                    u32* __restrict__ recs,
                                                    const float* __restrict__ x,
                                                    const float* __restrict__ w1,
                                                    const float* __restrict__ root1,
                                                    const float* __restrict__ b1,
                                                    uint4* __restrict__ h1b) {
    __shared__ u32 lc2[128];         // per-node cursor (relative)
    __shared__ u32 cnt32[CNTW];      // per-(node,rel) u8 counts packed 4/word
    __shared__ u32 sh[128];          // inclusive degree scan (survives all phases)
    __shared__ u32 lrec[CAP];        // sorted recs mirror for phase E
    int tid = threadIdx.x;
    int b = blockIdx.x;
    u32 r0 = (u32)b * CAP;
    u32 r1 = r0 + ccursor[b];        // per-bucket edge count from scan_kernel

    for (int i = tid; i < CNTW; i += 512) cnt32[i] = 0;
    __syncthreads();

    // A': issue ALL loads first (12 in flight), then consume with atomics
    u32 cached[12];                  // CAP/512 = 12 max entries per thread
#pragma unroll
    for (int i = 0; i < 12; i++) {
        u32 k = r0 + (u32)tid + (u32)i * 512u;
        cached[i] = (k < r1) ? tmp[k] : 0xFFFFFFFFu;
    }
#pragma unroll
    for (int i = 0; i < 12; i++) {
        u32 v = cached[i];
        if (v != 0xFFFFFFFFu) {
            u32 ln = v >> 25, rel = v & 127u;
            atomicAdd(&cnt32[ln * 23 + (rel >> 2)], 1u << ((rel & 3u) * 8u));
        }
    }
    __syncthreads();

    // A2: per-node degree = bytewise sum of own 23-word slice (no atomics)
    if (tid < 128) {
        u32 s = 0;
#pragma unroll
        for (int i = 0; i < 23; i++) {
            u32 w = cnt32[tid * 23 + i];
            s += (w & 255u) + ((w >> 8) & 255u) + ((w >> 16) & 255u) + (w >> 24);
        }
        sh[tid] = s;
    }
    __syncthreads();

    // B: inclusive scan of degrees (128 entries)
#pragma unroll
    for (int ofs = 1; ofs < 128; ofs <<= 1) {
        u32 v = (tid >= ofs && tid < 128) ? sh[tid - ofs] : 0u;
        __syncthreads();
        if (tid < 128) sh[tid] += v;
        __syncthreads();
    }
    int n = b * 128 + tid;
    if (tid < 128) {
        u32 excl = (tid == 0) ? 0u : sh[tid - 1];
        u32 deg = sh[tid] - excl;
        if (n < NN) off2[n] = (deg << 23) | (r0 + excl);   // start < 2^23, deg < 2^9
        lc2[tid] = excl;
    }
    __syncthreads();

    // C: scatter final recs — cnt32 complete, embed count byte; mirror into LDS
#pragma unroll
    for (int i = 0; i < 12; i++) {
        u32 v = cached[i];
        if (v != 0xFFFFFFFFu) {
            u32 ln = v >> 25, rel = v & 127u;
            u32 c = (cnt32[ln * 23 + (rel >> 2)] >> ((rel & 3u) * 8u)) & 255u;
            u32 pos = atomicAdd(&lc2[ln], 1u);
            u32 rr = (c << 24) | (v & 0xFFFFFFu);
            recs[r0 + pos] = rr;
            lrec[pos] = rr;
        }
    }
    __syncthreads();

    // E: layer 1 for this bucket's 128 nodes — 8 lanes/node, recs from LDS
#pragma unroll
    for (int g = 0; g < 2; g++) {
        int ln = g * 64 + (tid >> 3);          // 0..127
        int r = tid & 7;
        int nn = b * 128 + ln;
        float acc[8];
#pragma unroll
        for (int j = 0; j < 8; j++) acc[j] = 0.0f;
        if (nn < NN) {
            u32 k0l = (ln == 0) ? 0u : sh[ln - 1];
            u32 k1l = sh[ln];
            for (u32 k = k0l + r; k < k1l; k += 8) {
                u32 rec = lrec[k];
                u32 t = rec & 127u, s = (rec >> 7) & 0x1FFFFu;
                float norm = 1.0f / (float)(rec >> 24);
                float4 xv = *(const float4*)(x + (size_t)s * 4);
                float x0 = xv.x * norm, x1 = xv.y * norm;
                float x2 = xv.z * norm, x3 = xv.w * norm;
                const float4* wp = (const float4*)(w1 + (size_t)t * 16);  // [2][2][4]
                float4 wA = wp[0], wB = wp[1], wC = wp[2], wD = wp[3];
                acc[0] += x0 * wA.x + x1 * wB.x;
                acc[1] += x0 * wA.y + x1 * wB.y;
                acc[2] += x0 * wA.z + x1 * wB.z;
                acc[3] += x0 * wA.w + x1 * wB.w;
                acc[4] += x2 * wC.x + x3 * wD.x;
                acc[5] += x2 * wC.y + x3 * wD.y;
                acc[6] += x2 * wC.z + x3 * wD.z;
                acc[7] += x2 * wC.w + x3 * wD.w;
            }
        }
#pragma unroll
        for (int j = 0; j < 8; j++) {
            acc[j] += __shfl_xor(acc[j], 1);
            acc[j] += __shfl_xor(acc[j], 2);
            acc[j] += __shfl_xor(acc[j], 4);
        }
        if (r == 0 && nn < NN) {
            float4 xn = *(const float4*)(x + (size_t)nn * 4);
            float h[8];
#pragma unroll
            for (int j = 0; j < 8; j++) {
                float v = acc[j] + b1[j] + xn.x * root1[j] + xn.y * root1[8 + j]
                        + xn.z * root1[16 + j] + xn.w * root1[24 + j];
                h[j] = fmaxf(v, 0.0f);
            }
            h1b[nn] = make_uint4(pack2(h[0], h[1]), pack2(h[2], h[3]),
                                 pack2(h[4], h[5]), pack2(h[6], h[7]));
        }
    }
}

// ======== layers 2/3: 32 lanes/node (shallow gather chain), bf16 tables ========

// ---------------- layer 2: add-aggr + root + bias + relu ----------------
__global__ __launch_bounds__(256) void layer2_kernel(
        const u32* __restrict__ off2, const u32* __restrict__ recs,
        const uint4* __restrict__ h1b,
        const float* __restrict__ w2, const float* __restrict__ root2,
        const float* __restrict__ b2, u32* __restrict__ h2b) {
    int gid = blockIdx.x * 256 + threadIdx.x;
    int n = gid >> 5, r = gid & 31;
    if (n >= NN) return;
    float acc[12];
#pragma unroll
    for (int j = 0; j < 12; j++) acc[j] = 0.0f;

    u32 ov = off2[n];
    u32 k0 = ov & 0x7FFFFFu;
    u32 k1 = k0 + (ov >> 23);
    for (u32 k = k0 + r; k < k1; k += 32) {
        u32 rec = recs[k];
        u32 t = rec & 127u, s = (rec >> 7) & 0x1FFFFu;
        uint4 hw = h1b[s];
        float a0 = unlo(hw.x), a1 = unhi(hw.x), a2 = unlo(hw.y), a3 = unhi(hw.y);
        float a4 = unlo(hw.z), a5 = unhi(hw.z), a6 = unlo(hw.w), a7 = unhi(hw.w);
        const float4* wp = (const float4*)(w2 + (size_t)t * 24);   // [4][2][3]
        float4 w0 = wp[0], w1v = wp[1], w2v = wp[2], w3v = wp[3], w4v = wp[4], w5v = wp[5];
        acc[0]  += a0 * w0.x  + a1 * w0.w;
        acc[1]  += a0 * w0.y  + a1 * w1v.x;
        acc[2]  += a0 * w0.z  + a1 * w1v.y;
        acc[3]  += a2 * w1v.z + a3 * w2v.y;
        acc[4]  += a2 * w1v.w + a3 * w2v.z;
        acc[5]  += a2 * w2v.x + a3 * w2v.w;
        acc[6]  += a4 * w3v.x + a5 * w3v.w;
        acc[7]  += a4 * w3v.y + a5 * w4v.x;
        acc[8]  += a4 * w3v.z + a5 * w4v.y;
        acc[9]  += a6 * w4v.z + a7 * w5v.y;
        acc[10] += a6 * w4v.w + a7 * w5v.z;
        acc[11] += a6 * w5v.x + a7 * w5v.w;
    }
#pragma unroll
    for (int j = 0; j < 12; j++) {
        acc[j] += __shfl_xor(acc[j], 1);
        acc[j] += __shfl_xor(acc[j], 2);
        acc[j] += __shfl_xor(acc[j], 4);
        acc[j] += __shfl_xor(acc[j], 8);
        acc[j] += __shfl_xor(acc[j], 16);
    }
    if (r != 0) return;
    uint4 hn = h1b[n];
    float hv[8] = { unlo(hn.x), unhi(hn.x), unlo(hn.y), unhi(hn.y),
                    unlo(hn.z), unhi(hn.z), unlo(hn.w), unhi(hn.w) };
    float h[12];
#pragma unroll
    for (int j = 0; j < 12; j++) {
        float v = acc[j] + b2[j];
#pragma unroll
        for (int i = 0; i < 8; i++) v += hv[i] * root2[i * 12 + j];
        h[j] = fmaxf(v, 0.0f);
    }
    u32* hb = h2b + (size_t)n * 8;             // 32B stride, 24B used
    *(uint4*)hb = make_uint4(pack2(h[0], h[1]), pack2(h[2], h[3]),
                             pack2(h[4], h[5]), pack2(h[6], h[7]));
    *(uint2*)(hb + 4) = make_uint2(pack2(h[8], h[9]), pack2(h[10], h[11]));
}

// ---------------- layer 3: mean-aggr + root + bias + log_softmax ----------------
__global__ __launch_bounds__(256) void layer3_kernel(
        const u32* __restrict__ off2, const u32* __restrict__ recs,
        const u32* __restrict__ h2b,
        const float* __restrict__ w3, const float* __restrict__ root3,
        const float* __restrict__ b3, float* __restrict__ out) {
    int gid = blockIdx.x * 256 + threadIdx.x;
    int n = gid >> 5, r = gid & 31;
    if (n >= NN) return;
    float acc[4] = {0.0f, 0.0f, 0.0f, 0.0f};
    u32 ov = off2[n];
    u32 k0 = ov & 0x7FFFFFu;
    u32 k1 = k0 + (ov >> 23);
    for (u32 k = k0 + r; k < k1; k += 32) {
        u32 rec = recs[k];
        u32 t = rec & 127u, s = (rec >> 7) & 0x1FFFFu;
        float norm = 1.0f / (float)(rec >> 24);
        const u32* hb = h2b + (size_t)s * 8;
        uint4 q = *(const uint4*)hb;
        uint2 p = *(const uint2*)(hb + 4);
        float hsv[12] = { unlo(q.x), unhi(q.x), unlo(q.y), unhi(q.y),
                          unlo(q.z), unhi(q.z), unlo(q.w), unhi(q.w),
                          unlo(p.x), unhi(p.x), unlo(p.y), unhi(p.y) };
        float wv[24];
        const float4* wp = (const float4*)(w3 + (size_t)t * 24);   // [2][6][2]
#pragma unroll
        for (int q4 = 0; q4 < 6; q4++) *(float4*)(wv + q4 * 4) = wp[q4];
        float m0 = 0.0f, m1 = 0.0f, m2 = 0.0f, m3 = 0.0f;
#pragma unroll
        for (int i = 0; i < 6; i++) {
            m0 += hsv[i] * wv[i * 2];          m1 += hsv[i] * wv[i * 2 + 1];
            m2 += hsv[6 + i] * wv[12 + i * 2]; m3 += hsv[6 + i] * wv[12 + i * 2 + 1];
        }
        acc[0] += m0 * norm; acc[1] += m1 * norm;
        acc[2] += m2 * norm; acc[3] += m3 * norm;
    }
#pragma unroll
    for (int j = 0; j < 4; j++) {
        acc[j] += __shfl_xor(acc[j], 1);
        acc[j] += __shfl_xor(acc[j], 2);
        acc[j] += __shfl_xor(acc[j], 4);
        acc[j] += __shfl_xor(acc[j], 8);
        acc[j] += __shfl_xor(acc[j], 16);
    }
    if (r != 0) return;
    const u32* hbn = h2b + (size_t)n * 8;
    uint4 qn = *(const uint4*)hbn; uint2 pn = *(const uint2*)(hbn + 4);
    float hv[12] = { unlo(qn.x), unhi(qn.x), unlo(qn.y), unhi(qn.y),
                     unlo(qn.z), unhi(qn.z), unlo(qn.w), unhi(qn.w),
                     unlo(pn.x), unhi(pn.x), unlo(pn.y), unhi(pn.y) };
    float t4[4];
#pragma unroll
    for (int j = 0; j < 4; j++) {
        float v = acc[j] + b3[j];
#pragma unroll
        for (int i = 0; i < 12; i++) v += hv[i] * root3[i * 4 + j];
        t4[j] = v;
    }
    float m = fmaxf(fmaxf(t4[0], t4[1]), fmaxf(t4[2], t4[3]));
    float s = 0.0f;
#pragma unroll
    for (int j = 0; j < 4; j++) s += __expf(t4[j] - m);
    float lse = m + __logf(s);
    *(float4*)(out + (size_t)n * 4) =
        make_float4(t4[0] - lse, t4[1] - lse, t4[2] - lse, t4[3] - lse);
}

extern "C" void kernel_launch(void* const* d_in, const int* in_sizes, int n_in,
                              void* d_out, int out_size, void* d_ws, size_t ws_size,
                              hipStream_t stream) {
    const float* x     = (const float*)d_in[0];
    const int*   ei    = (const int*)d_in[1];   // [2, E]
    const int*   etype = (const int*)d_in[2];
    const float* w1    = (const float*)d_in[3];
    const float* root1 = (const float*)d_in[4];
    const float* b1    = (const float*)d_in[5];
    const float* w2    = (const float*)d_in[6];
    const float* root2 = (const float*)d_in[7];
    const float* b2    = (const float*)d_in[8];
    const float* w3    = (const float*)d_in[9];
    const float* root3 = (const float*)d_in[10];
    const float* b3    = (const float*)d_in[11];
    float* out = (float*)d_out;

    const int* src = ei;
    const int* dst = ei + NE;

    // workspace layout (bytes):
    //   bucketcnt: [NB]     u32   @ 0           (3,128 -> pad 3,200)
    //   off2    : [NN]      u32   @ 3,200       (400,000 -> ends 403,200)
    //   tmp     : [NB*CAP]  u32   @ 403,200     (19,218,432 -> ends 19,621,632)
    //   recs    : [NB*CAP]  u32   @ 19,621,632  (19,218,432 -> ends 38,840,064)
    //     cntmat: [NCHUNK*NB] u32 @ 19,621,632  (2,446,096) -- overlays recs, dead after P1c
    //     offT  : [NB*NCHUNK] u32 @ 22,067,728  (2,446,096) -- overlays recs, dead after P1c
    //   h1b     : [NN]      16B   @ 38,840,064  ( 1,600,000 -> ends 40,440,064)
    //   h2b     : [NN]      32B   @ 40,440,064  ( 3,200,000 -> total 43,640,064)
    char* ws = (char*)d_ws;
    u32*   bucketcnt = (u32*)ws;
    u32*   off2    = (u32*)(ws + 3200);
    u32*   tmp     = (u32*)(ws + 403200);
    u32*   recs    = (u32*)(ws + 19621632);
    u32*   cntmat  = (u32*)(ws + 19621632);
    u32*   offT    = (u32*)(ws + 22067728);
    uint4* h1b     = (uint4*)(ws + 38840064);
    u32*   h2b     = (u32*)(ws + 40440064);

    dim3 pgrid(NCHUNK);                      // 782
    dim3 ngrid(NB);                          // 782
    dim3 lgrid((NN * 32 + 255) / 256);       // 12500 (32 lanes/node)

    count_kernel<<<pgrid, 512, 0, stream>>>(dst, cntmat);
    scan_kernel<<<dim3(NB), 512, 0, stream>>>(cntmat, offT, bucketcnt);
    scatter_kernel<<<pgrid, 512, 0, stream>>>(src, dst, etype, cntmat, offT, tmp);
    pass2_kernel<<<ngrid, 512, 0, stream>>>(tmp, bucketcnt, off2, recs, x, w1, root1, b1, h1b);
    layer2_kernel<<<lgrid, 256, 0, stream>>>(off2, recs, h1b, w2, root2, b2, h2b);
    layer3_kernel<<<lgrid, 256, 0, stream>>>(off2, recs, h2b, w3, root3, b3, out);
}

// Round 3
// 248.166 us; speedup vs baseline: 1.1248x; 1.0382x over previous
//
#include <hip/hip_runtime.h>
#include <math.h>

#define NN 100000
#define NE 3200000
#define NR 90
#define NB 782          // buckets of 128 nodes (dst>>7)
#define CH 4096         // edges per chunk
#define NCHUNK 782      // ceil(NE/CH)
#define CAP 6144        // padded per-bucket capacity (mean 4096, +32 sigma)

typedef unsigned int u32;
typedef unsigned short u16;

__device__ inline u16 bf16r(float a) {                 // f32 -> bf16 (RNE)
    u32 ua = __float_as_uint(a); ua += 0x7FFFu + ((ua >> 16) & 1u);
    return (u16)(ua >> 16);
}
__device__ inline float unlo(u32 w) { return __uint_as_float(w << 16); }
__device__ inline float unhi(u32 w) { return __uint_as_float(w & 0xFFFF0000u); }

// ============ pass 1 (deterministic, ZERO global atomics) ============
// P1a: per-chunk histogram -> cntmat[chunk][NB]
__global__ __launch_bounds__(512) void count_kernel(const int* __restrict__ dst,
                                                    u32* __restrict__ cntmat) {
    __shared__ u32 cntA[NB];
    int tid = threadIdx.x;
    int c0 = blockIdx.x * CH;
    int c1 = c0 + CH; if (c1 > NE) c1 = NE;
    for (int i = tid; i < NB; i += 512) cntA[i] = 0;
    __syncthreads();
    for (int e = c0 + tid; e < c1; e += 512)
        atomicAdd(&cntA[(u32)dst[e] >> 7], 1u);
    __syncthreads();
    for (int i = tid; i < NB; i += 512)
        cntmat[(size_t)blockIdx.x * NB + i] = cntA[i];
}

// P1b: per-bucket exclusive scan over chunks -> offT[bucket][NCHUNK]; totals -> bucketcnt
__global__ __launch_bounds__(512) void scan_kernel(const u32* __restrict__ cntmat,
                                                   u32* __restrict__ offT,
                                                   u32* __restrict__ bucketcnt) {
    __shared__ u32 scanS[512];
    int tid = threadIdx.x, b = blockIdx.x;
    int c0 = 2 * tid, c1 = 2 * tid + 1;
    u32 a  = (c0 < NCHUNK) ? cntmat[(size_t)c0 * NB + b] : 0u;
    u32 bb = (c1 < NCHUNK) ? cntmat[(size_t)c1 * NB + b] : 0u;
    scanS[tid] = a + bb;
    __syncthreads();
#pragma unroll
    for (int ofs = 1; ofs < 512; ofs <<= 1) {
        u32 v = (tid >= ofs) ? scanS[tid - ofs] : 0u;
        __syncthreads();
        scanS[tid] += v;
        __syncthreads();
    }
    u32 excl = (tid == 0) ? 0u : scanS[tid - 1];
    if (c0 < NCHUNK) offT[(size_t)b * NCHUNK + c0] = excl;
    if (c1 < NCHUNK) offT[(size_t)b * NCHUNK + c1] = excl + a;
    if (tid == (NCHUNK - 1) / 2) bucketcnt[b] = scanS[(NCHUNK - 1) / 2];
}

// P1c: scatter with precomputed bases; LDS-staged coalesced global write
// tmp entry: (dst&127)<<25 | src<<7 | et ; bucket b's window is tmp[b*CAP ..]
__global__ __launch_bounds__(512) void scatter_kernel(const int* __restrict__ src,
                                                      const int* __restrict__ dst,
                                                      const int* __restrict__ et,
                                                      const u32* __restrict__ cntmat,
                                                      const u32* __restrict__ offT,
                                                      u32* __restrict__ tmp) {
    __shared__ u32 lcur[NB];
    __shared__ u32 delta[NB];
    __shared__ u32 scanS[512];
    __shared__ u32 lrecs[CH];
    __shared__ u16 lbid[CH];
    int tid = threadIdx.x, ck = blockIdx.x;
    int c0 = ck * CH;
    int c1 = c0 + CH; if (c1 > NE) c1 = NE;
    int nloc = c1 - c0;

    // local scan of this chunk's bucket counts (read from cntmat, no recount)
    int i0 = 2 * tid, i1 = 2 * tid + 1;
    u32 ca = (i0 < NB) ? cntmat[(size_t)ck * NB + i0] : 0u;
    u32 cb = (i1 < NB) ? cntmat[(size_t)ck * NB + i1] : 0u;
    scanS[tid] = ca + cb;
    __syncthreads();
#pragma unroll
    for (int ofs = 1; ofs < 512; ofs <<= 1) {
        u32 v = (tid >= ofs) ? scanS[tid - ofs] : 0u;
        __syncthreads();
        scanS[tid] += v;
        __syncthreads();
    }
    u32 exc = (tid == 0) ? 0u : scanS[tid - 1];
    if (i0 < NB) {
        lcur[i0] = exc;
        delta[i0] = (u32)i0 * CAP + offT[(size_t)i0 * NCHUNK + ck] - exc;
    }
    if (i1 < NB) {
        u32 e1 = exc + ca;
        lcur[i1] = e1;
        delta[i1] = (u32)i1 * CAP + offT[(size_t)i1 * NCHUNK + ck] - e1;
    }
    __syncthreads();

    for (int e = c0 + tid; e < c1; e += 512) {
        u32 d = (u32)dst[e];
        u32 b = d >> 7;
        u32 pos = atomicAdd(&lcur[b], 1u);
        lrecs[pos] = ((d & 127u) << 25) | ((u32)src[e] << 7) | (u32)et[e];
        lbid[pos] = (u16)b;
    }
    __syncthreads();

    for (int k = tid; k < nloc; k += 512)
        tmp[delta[lbid[k]] + k] = lrecs[k];
}

// ---------------- pass 2 + layer 1 fused (512 threads, 128-node bucket) ----------------
#define CNTW (128 * 23)
__global__ __launch_bounds__(512) void pass2_kernel(const u32* __restrict__ tmp,
                                                    const u32* __restrict__ ccursor,
                                                    u32* __restrict__ off2,
                                                    u32* __restrict__ recs,
                                                    const float* __restrict__ x,
                                                    const float* __restrict__ w1,
                                                    const float* __restrict__ root1,
                                                    const float* __restrict__ b1,
                                                    float* __restrict__ h1) {
    __shared__ u32 lc2[128];         // per-node cursor (relative)
    __shared__ u32 cnt32[CNTW];      // per-(node,rel) u8 counts packed 4/word
    __shared__ u32 sh[128];          // inclusive degree scan (survives all phases)
    __shared__ u32 lrec[CAP];        // sorted recs mirror for phase E
    int tid = threadIdx.x;
    int b = blockIdx.x;
    u32 r0 = (u32)b * CAP;
    u32 r1 = r0 + ccursor[b];        // per-bucket edge count from scan_kernel

    for (int i = tid; i < CNTW; i += 512) cnt32[i] = 0;
    __syncthreads();

    // A': issue ALL loads first (12 in flight), then consume with atomics
    u32 cached[12];                  // CAP/512 = 12 max entries per thread
#pragma unroll
    for (int i = 0; i < 12; i++) {
        u32 k = r0 + (u32)tid + (u32)i * 512u;
        cached[i] = (k < r1) ? tmp[k] : 0xFFFFFFFFu;
    }
#pragma unroll
    for (int i = 0; i < 12; i++) {
        u32 v = cached[i];
        if (v != 0xFFFFFFFFu) {
            u32 ln = v >> 25, rel = v & 127u;
            atomicAdd(&cnt32[ln * 23 + (rel >> 2)], 1u << ((rel & 3u) * 8u));
        }
    }
    __syncthreads();

    // A2: per-node degree = bytewise sum of own 23-word slice (no atomics)
    if (tid < 128) {
        u32 s = 0;
#pragma unroll
        for (int i = 0; i < 23; i++) {
            u32 w = cnt32[tid * 23 + i];
            s += (w & 255u) + ((w >> 8) & 255u) + ((w >> 16) & 255u) + (w >> 24);
        }
        sh[tid] = s;
    }
    __syncthreads();

    // B: inclusive scan of degrees (128 entries)
#pragma unroll
    for (int ofs = 1; ofs < 128; ofs <<= 1) {
        u32 v = (tid >= ofs && tid < 128) ? sh[tid - ofs] : 0u;
        __syncthreads();
        if (tid < 128) sh[tid] += v;
        __syncthreads();
    }
    int n = b * 128 + tid;
    if (tid < 128) {
        u32 excl = (tid == 0) ? 0u : sh[tid - 1];
        u32 deg = sh[tid] - excl;
        if (n < NN) off2[n] = (deg << 23) | (r0 + excl);   // start < 2^23, deg < 2^9
        lc2[tid] = excl;
    }
    __syncthreads();

    // C: scatter final recs — cnt32 complete, embed count byte; mirror into LDS
#pragma unroll
    for (int i = 0; i < 12; i++) {
        u32 v = cached[i];
        if (v != 0xFFFFFFFFu) {
            u32 ln = v >> 25, rel = v & 127u;
            u32 c = (cnt32[ln * 23 + (rel >> 2)] >> ((rel & 3u) * 8u)) & 255u;
            u32 pos = atomicAdd(&lc2[ln], 1u);
            u32 rr = (c << 24) | (v & 0xFFFFFFu);
            recs[r0 + pos] = rr;
            lrec[pos] = rr;
        }
    }
    __syncthreads();

    // E: layer 1 for this bucket's 128 nodes — 8 lanes/node, recs from LDS,
    //    distributed epilogue (lane r computes + stores output feature r, f32)
#pragma unroll
    for (int g = 0; g < 2; g++) {
        int ln = g * 64 + (tid >> 3);          // 0..127
        int r = tid & 7;
        int nn = b * 128 + ln;
        float acc[8];
#pragma unroll
        for (int j = 0; j < 8; j++) acc[j] = 0.0f;
        if (nn < NN) {
            u32 k0l = (ln == 0) ? 0u : sh[ln - 1];
            u32 k1l = sh[ln];
            for (u32 k = k0l + r; k < k1l; k += 8) {
                u32 rec = lrec[k];
                u32 t = rec & 127u, s = (rec >> 7) & 0x1FFFFu;
                float norm = 1.0f / (float)(rec >> 24);
                float4 xv = *(const float4*)(x + (size_t)s * 4);
                float x0 = xv.x * norm, x1 = xv.y * norm;
                float x2 = xv.z * norm, x3 = xv.w * norm;
                const float4* wp = (const float4*)(w1 + (size_t)t * 16);  // [2][2][4]
                float4 wA = wp[0], wB = wp[1], wC = wp[2], wD = wp[3];
                acc[0] += x0 * wA.x + x1 * wB.x;
                acc[1] += x0 * wA.y + x1 * wB.y;
                acc[2] += x0 * wA.z + x1 * wB.z;
                acc[3] += x0 * wA.w + x1 * wB.w;
                acc[4] += x2 * wC.x + x3 * wD.x;
                acc[5] += x2 * wC.y + x3 * wD.y;
                acc[6] += x2 * wC.z + x3 * wD.z;
                acc[7] += x2 * wC.w + x3 * wD.w;
            }
        }
#pragma unroll
        for (int j = 0; j < 8; j++) {
            acc[j] += __shfl_xor(acc[j], 1);
            acc[j] += __shfl_xor(acc[j], 2);
            acc[j] += __shfl_xor(acc[j], 4);
        }
        if (nn < NN) {
            float4 xn = *(const float4*)(x + (size_t)nn * 4);
            float v = acc[r] + b1[r] + xn.x * root1[r] + xn.y * root1[8 + r]
                    + xn.z * root1[16 + r] + xn.w * root1[24 + r];
            h1[(size_t)nn * 8 + r] = fmaxf(v, 0.0f);
        }
    }
}

// ======== layers 2/3: 16 lanes/node, LDS weights, distributed epilogues ========

// ---------------- layer 2: add-aggr + root + bias + relu ----------------
__global__ __launch_bounds__(256) void layer2_kernel(
        const u32* __restrict__ off2, const u32* __restrict__ recs,
        const float* __restrict__ h1,            // [NN][8] f32
        const float* __restrict__ w2, const float* __restrict__ root2,
        const float* __restrict__ b2, u16* __restrict__ h2b) {  // [NN][16] bf16
    __shared__ float4 w2s[NR * 6];               // [R][4][2][3] as 6 float4/rel
    int tid = threadIdx.x;
    for (int i = tid; i < NR * 6; i += 256) w2s[i] = ((const float4*)w2)[i];
    __syncthreads();

    int gid = blockIdx.x * 256 + tid;
    int n = gid >> 4, r = gid & 15;
    if (n >= NN) return;
    float acc[12];
#pragma unroll
    for (int j = 0; j < 12; j++) acc[j] = 0.0f;

    u32 ov = off2[n];
    u32 k0 = ov & 0x7FFFFFu;
    u32 k1 = k0 + (ov >> 23);
    for (u32 k = k0 + r; k < k1; k += 16) {
        u32 rec = recs[k];
        u32 t = rec & 127u, s = (rec >> 7) & 0x1FFFFu;
        float4 ha = *(const float4*)(h1 + (size_t)s * 8);
        float4 hb = *(const float4*)(h1 + (size_t)s * 8 + 4);
        const float4* wp = &w2s[t * 6];
        float4 w0 = wp[0], w1v = wp[1], w2v = wp[2], w3v = wp[3], w4v = wp[4], w5v = wp[5];
        acc[0]  += ha.x * w0.x  + ha.y * w0.w;
        acc[1]  += ha.x * w0.y  + ha.y * w1v.x;
        acc[2]  += ha.x * w0.z  + ha.y * w1v.y;
        acc[3]  += ha.z * w1v.z + ha.w * w2v.y;
        acc[4]  += ha.z * w1v.w + ha.w * w2v.z;
        acc[5]  += ha.z * w2v.x + ha.w * w2v.w;
        acc[6]  += hb.x * w3v.x + hb.y * w3v.w;
        acc[7]  += hb.x * w3v.y + hb.y * w4v.x;
        acc[8]  += hb.x * w3v.z + hb.y * w4v.y;
        acc[9]  += hb.z * w4v.z + hb.w * w5v.y;
        acc[10] += hb.z * w4v.w + hb.w * w5v.z;
        acc[11] += hb.z * w5v.x + hb.w * w5v.w;
    }
#pragma unroll
    for (int j = 0; j < 12; j++) {
        acc[j] += __shfl_xor(acc[j], 1);
        acc[j] += __shfl_xor(acc[j], 2);
        acc[j] += __shfl_xor(acc[j], 4);
        acc[j] += __shfl_xor(acc[j], 8);
    }
    if (r < 12) {
        float4 xa = *(const float4*)(h1 + (size_t)n * 8);
        float4 xb = *(const float4*)(h1 + (size_t)n * 8 + 4);
        float v = acc[r] + b2[r]
                + xa.x * root2[r]      + xa.y * root2[12 + r]
                + xa.z * root2[24 + r] + xa.w * root2[36 + r]
                + xb.x * root2[48 + r] + xb.y * root2[60 + r]
                + xb.z * root2[72 + r] + xb.w * root2[84 + r];
        h2b[(size_t)n * 16 + r] = bf16r(fmaxf(v, 0.0f));
    }
}

// ---------------- layer 3: mean-aggr + root + bias + log_softmax ----------------
__global__ __launch_bounds__(256) void layer3_kernel(
        const u32* __restrict__ off2, const u32* __restrict__ recs,
        const u16* __restrict__ h2b,             // [NN][16] bf16 (12 used)
        const float* __restrict__ w3, const float* __restrict__ root3,
        const float* __restrict__ b3, float* __restrict__ out) {
    __shared__ float4 w3s[NR * 6];               // [R][2][6][2] as 6 float4/rel
    int tid = threadIdx.x;
    for (int i = tid; i < NR * 6; i += 256) w3s[i] = ((const float4*)w3)[i];
    __syncthreads();

    int gid = blockIdx.x * 256 + tid;
    int n = gid >> 4, r = gid & 15;
    if (n >= NN) return;
    float acc[4] = {0.0f, 0.0f, 0.0f, 0.0f};
    u32 ov = off2[n];
    u32 k0 = ov & 0x7FFFFFu;
    u32 k1 = k0 + (ov >> 23);
    for (u32 k = k0 + r; k < k1; k += 16) {
        u32 rec = recs[k];
        u32 t = rec & 127u, s = (rec >> 7) & 0x1FFFFu;
        float norm = 1.0f / (float)(rec >> 24);
        const u16* hbp = h2b + (size_t)s * 16;
        uint4 q = *(const uint4*)hbp;
        uint2 p = *(const uint2*)(hbp + 8);
        float hsv[12] = { unlo(q.x), unhi(q.x), unlo(q.y), unhi(q.y),
                          unlo(q.z), unhi(q.z), unlo(q.w), unhi(q.w),
                          unlo(p.x), unhi(p.x), unlo(p.y), unhi(p.y) };
        const float4* wp = &w3s[t * 6];
        float wv[24];
#pragma unroll
        for (int q4 = 0; q4 < 6; q4++) *(float4*)(wv + q4 * 4) = wp[q4];
        float m0 = 0.0f, m1 = 0.0f, m2 = 0.0f, m3 = 0.0f;
#pragma unroll
        for (int i = 0; i < 6; i++) {
            m0 += hsv[i] * wv[i * 2];          m1 += hsv[i] * wv[i * 2 + 1];
            m2 += hsv[6 + i] * wv[12 + i * 2]; m3 += hsv[6 + i] * wv[12 + i * 2 + 1];
        }
        acc[0] += m0 * norm; acc[1] += m1 * norm;
        acc[2] += m2 * norm; acc[3] += m3 * norm;
    }
#pragma unroll
    for (int j = 0; j < 4; j++) {
        acc[j] += __shfl_xor(acc[j], 1);
        acc[j] += __shfl_xor(acc[j], 2);
        acc[j] += __shfl_xor(acc[j], 4);
        acc[j] += __shfl_xor(acc[j], 8);
    }
    if (r < 4) {
        const u16* hbn = h2b + (size_t)n * 16;
        uint4 qn = *(const uint4*)hbn;
        uint2 pn = *(const uint2*)(hbn + 8);
        float hv[12] = { unlo(qn.x), unhi(qn.x), unlo(qn.y), unhi(qn.y),
                         unlo(qn.z), unhi(qn.z), unlo(qn.w), unhi(qn.w),
                         unlo(pn.x), unhi(pn.x), unlo(pn.y), unhi(pn.y) };
        float v = acc[r] + b3[r];
#pragma unroll
        for (int i = 0; i < 12; i++) v += hv[i] * root3[i * 4 + r];
        float mx = v;
        mx = fmaxf(mx, __shfl_xor(mx, 1));
        mx = fmaxf(mx, __shfl_xor(mx, 2));
        float e = __expf(v - mx);
        float sm = e;
        sm += __shfl_xor(sm, 1);
        sm += __shfl_xor(sm, 2);
        out[(size_t)n * 4 + r] = v - mx - __logf(sm);
    }
}

extern "C" void kernel_launch(void* const* d_in, const int* in_sizes, int n_in,
                              void* d_out, int out_size, void* d_ws, size_t ws_size,
                              hipStream_t stream) {
    const float* x     = (const float*)d_in[0];
    const int*   ei    = (const int*)d_in[1];   // [2, E]
    const int*   etype = (const int*)d_in[2];
    const float* w1    = (const float*)d_in[3];
    const float* root1 = (const float*)d_in[4];
    const float* b1    = (const float*)d_in[5];
    const float* w2    = (const float*)d_in[6];
    const float* root2 = (const float*)d_in[7];
    const float* b2    = (const float*)d_in[8];
    const float* w3    = (const float*)d_in[9];
    const float* root3 = (const float*)d_in[10];
    const float* b3    = (const float*)d_in[11];
    float* out = (float*)d_out;

    const int* src = ei;
    const int* dst = ei + NE;

    // workspace layout (bytes):
    //   bucketcnt: [NB]     u32   @ 0           (3,128 -> pad 3,200)
    //   off2    : [NN]      u32   @ 3,200       (400,000 -> ends 403,200)
    //   tmp     : [NB*CAP]  u32   @ 403,200     (19,218,432 -> ends 19,621,632)
    //     h2b   : [NN][16]  u16   @ 403,200     (3,200,000) -- overlays tmp (dead after pass2)
    //   recs    : [NB*CAP]  u32   @ 19,621,632  (19,218,432 -> ends 38,840,064)
    //     cntmat: [NCHUNK*NB] u32 @ 19,621,632  (2,446,096) -- overlays recs, dead after P1c
    //     offT  : [NB*NCHUNK] u32 @ 22,067,728  (2,446,096) -- overlays recs, dead after P1c
    //   h1      : [NN][8]   f32   @ 38,840,064  (3,200,000 -> total 42,040,064)
    char* ws = (char*)d_ws;
    u32*   bucketcnt = (u32*)ws;
    u32*   off2    = (u32*)(ws + 3200);
    u32*   tmp     = (u32*)(ws + 403200);
    u16*   h2b     = (u16*)(ws + 403200);
    u32*   recs    = (u32*)(ws + 19621632);
    u32*   cntmat  = (u32*)(ws + 19621632);
    u32*   offT    = (u32*)(ws + 22067728);
    float* h1      = (float*)(ws + 38840064);

    dim3 pgrid(NCHUNK);                      // 782
    dim3 ngrid(NB);                          // 782
    dim3 lgrid((NN * 16 + 255) / 256);       // 6250 (16 lanes/node)

    count_kernel<<<pgrid, 512, 0, stream>>>(dst, cntmat);
    scan_kernel<<<dim3(NB), 512, 0, stream>>>(cntmat, offT, bucketcnt);
    scatter_kernel<<<pgrid, 512, 0, stream>>>(src, dst, etype, cntmat, offT, tmp);
    pass2_kernel<<<ngrid, 512, 0, stream>>>(tmp, bucketcnt, off2, recs, x, w1, root1, b1, h1);
    layer2_kernel<<<lgrid, 256, 0, stream>>>(off2, recs, h1, w2, root2, b2, h2b);
    layer3_kernel<<<lgrid, 256, 0, stream>>>(off2, recs, h2b, w3, root3, b3, out);
}